// Round 2
// 854.335 us; speedup vs baseline: 1.3111x; 1.3111x over previous
//
#include <hip/hip_runtime.h>
#include <cstdint>
#include <cstddef>

#define B_N   8
#define C_N   256
#define H_N   128
#define W_N   128
#define S_N   16384          // H*W
#define CS_N  4194304        // C*S
#define NELEM 33554432       // B*C*S
#define EPS_F 1e-5f

// ---------------------------------------------------------------------------
// Kernel 1: 1x1 conv as GEMM.  Y[b,o,s] = sum_c W[o,c] * X[b,c,s]
// tile 128(o) x 128(s), K-step 16, 8x8 micro-tile, fp32 LDS, fp32 accum.
// Output spatial layout per tensor:
//   tensor 0 (qf -> d_out): STANDARD s (row-major H*W)  [must match out layout]
//   tensor 1 (kf -> ws)   : PATCH-MAJOR s' = patch*64 + r*8 + q
// Patch-major kf makes attn's k reads fully contiguous (256B/channel/patch).
// ---------------------------------------------------------------------------
__global__ __launch_bounds__(256) void conv_gemm(
    const float* __restrict__ x_low, const float* __restrict__ x_high,
    const float* __restrict__ Wq, const float* __restrict__ Wk,
    float* __restrict__ qf, float* __restrict__ kf)
{
  const int tid = threadIdx.x;
  const int tx = tid & 15, ty = tid >> 4;
  const int s0 = blockIdx.x * 128;
  const int o0 = blockIdx.y * 128;
  const int tensor = blockIdx.z >> 3;
  const int b = blockIdx.z & 7;

  const float* __restrict__ X = tensor ? x_high : x_low;
  const float* __restrict__ Wm = tensor ? Wk : Wq;
  float* __restrict__ Y = tensor ? kf : qf;

  __shared__ float As[16][128];  // As[k][o]
  __shared__ float Bs[16][132];  // Bs[k][s], padded

  float acc[8][8];
#pragma unroll
  for (int i = 0; i < 8; ++i)
#pragma unroll
    for (int j = 0; j < 8; ++j) acc[i][j] = 0.0f;

  const size_t xbase = (size_t)b * CS_N;
  const int a_oo = tid >> 1;          // 0..127
  const int a_kk = (tid & 1) * 8;     // 0 or 8
  const int b_kk = tid >> 4;          // 0..15
  const int b_ss = (tid & 15) * 8;    // 0..120

  // input spatial address for this thread's 8 consecutive output s-indices.
  // For patch-major output, s' = nl*64 + r*8 + q maps to h = (nl>>4)*8 + r,
  // w = (nl&15)*8 + q; the 8 q's are contiguous (one 32B patch row).
  int hw;
  {
    const int sp = s0 + b_ss;         // multiple of 8
    if (tensor) {
      const int nl = sp >> 6;
      const int r  = (sp >> 3) & 7;
      hw = (((nl >> 4) << 3) + r) * W_N + ((nl & 15) << 3);
    } else {
      hw = sp;
    }
  }
  const size_t xoff = xbase + (size_t)hw;

  for (int k0 = 0; k0 < 256; k0 += 16) {
    __syncthreads();
    {
      const float* src = Wm + ((size_t)(o0 + a_oo) * 256 + k0 + a_kk);
      const float4 w0 = *reinterpret_cast<const float4*>(src);
      const float4 w1 = *reinterpret_cast<const float4*>(src + 4);
      As[a_kk + 0][a_oo] = w0.x; As[a_kk + 1][a_oo] = w0.y;
      As[a_kk + 2][a_oo] = w0.z; As[a_kk + 3][a_oo] = w0.w;
      As[a_kk + 4][a_oo] = w1.x; As[a_kk + 5][a_oo] = w1.y;
      As[a_kk + 6][a_oo] = w1.z; As[a_kk + 7][a_oo] = w1.w;
    }
    {
      const float* src = X + (xoff + (size_t)(k0 + b_kk) * S_N);
      const float4 x0 = *reinterpret_cast<const float4*>(src);
      const float4 x1 = *reinterpret_cast<const float4*>(src + 4);
      Bs[b_kk][b_ss + 0] = x0.x; Bs[b_kk][b_ss + 1] = x0.y;
      Bs[b_kk][b_ss + 2] = x0.z; Bs[b_kk][b_ss + 3] = x0.w;
      Bs[b_kk][b_ss + 4] = x1.x; Bs[b_kk][b_ss + 5] = x1.y;
      Bs[b_kk][b_ss + 6] = x1.z; Bs[b_kk][b_ss + 7] = x1.w;
    }
    __syncthreads();
#pragma unroll
    for (int kk = 0; kk < 16; ++kk) {
      const float4 a0 = *reinterpret_cast<const float4*>(&As[kk][ty * 8]);
      const float4 a1 = *reinterpret_cast<const float4*>(&As[kk][ty * 8 + 4]);
      const float4 b0 = *reinterpret_cast<const float4*>(&Bs[kk][tx * 4]);
      const float4 b1 = *reinterpret_cast<const float4*>(&Bs[kk][64 + tx * 4]);
      const float av[8] = {a0.x, a0.y, a0.z, a0.w, a1.x, a1.y, a1.z, a1.w};
      const float bv[8] = {b0.x, b0.y, b0.z, b0.w, b1.x, b1.y, b1.z, b1.w};
#pragma unroll
      for (int i = 0; i < 8; ++i)
#pragma unroll
        for (int j = 0; j < 8; ++j) acc[i][j] = fmaf(av[i], bv[j], acc[i][j]);
    }
  }

#pragma unroll
  for (int i = 0; i < 8; ++i) {
    float* row = Y + (xbase + (size_t)(o0 + ty * 8 + i) * S_N + s0);
    *reinterpret_cast<float4*>(row + tx * 4) =
        make_float4(acc[i][0], acc[i][1], acc[i][2], acc[i][3]);
    *reinterpret_cast<float4*>(row + 64 + tx * 4) =
        make_float4(acc[i][4], acc[i][5], acc[i][6], acc[i][7]);
  }
}

// ---------------------------------------------------------------------------
// Kernel 2: GroupNorm stats. One block per (tensor, b, g).
// Sums are invariant to the spatial permutation of kf, so unchanged.
// ---------------------------------------------------------------------------
__global__ __launch_bounds__(256) void gn_stats(
    const float* __restrict__ qf, const float* __restrict__ kf,
    float2* __restrict__ stats)
{
  const int bid = blockIdx.x;            // 0..511
  const int tensor = bid >> 8;
  const int rem = bid & 255;
  const int b = rem >> 5;
  const int g = rem & 31;
  const float* __restrict__ base =
      (tensor ? kf : qf) + (size_t)b * CS_N + (size_t)g * 8 * S_N;
  const float4* __restrict__ base4 = reinterpret_cast<const float4*>(base);

  const int tid = threadIdx.x;
  float s1 = 0.0f, s2 = 0.0f;
  for (int i = tid; i < 32768; i += 256) {
    const float4 u = base4[i];
    s1 += u.x + u.y + u.z + u.w;
    s2 += u.x * u.x + u.y * u.y + u.z * u.z + u.w * u.w;
  }
#pragma unroll
  for (int off = 32; off > 0; off >>= 1) {
    s1 += __shfl_down(s1, off);
    s2 += __shfl_down(s2, off);
  }
  __shared__ float r1[4], r2[4];
  const int wave = tid >> 6;
  if ((tid & 63) == 0) { r1[wave] = s1; r2[wave] = s2; }
  __syncthreads();
  if (tid == 0) {
    const float S1 = r1[0] + r1[1] + r1[2] + r1[3];
    const float S2 = r2[0] + r2[1] + r2[2] + r2[3];
    const float mean = S1 * (1.0f / 131072.0f);
    const float var = S2 * (1.0f / 131072.0f) - mean * mean;
    stats[bid] = make_float2(mean, rsqrtf(var + EPS_F));
  }
}

// ---------------------------------------------------------------------------
// Kernel 3: per-patch attention.
//  - k (patch-major) staged with contiguous float4 loads, GN applied inline.
//  - q (standard layout, lives in d_out) staged via scalar transpose.
//  - S computed as outer product over c: both operands [c][p] in LDS, all
//    fragment reads broadcast / 2-way (free).
//  - S stored TRANSPOSED (s_mat[r][p]) -> softmax reduction down rows is
//    lane-contiguous in p: conflict-free (was 8-way).
//  - PV stages k^T ([r][c]) and runs as outer product over r: conflict-free.
//  - XCD-contiguous patch swizzle: neighbor patches (sharing 64B half-lines
//    of qf/x_low/out) land on the same XCD's L2.
// LDS = 3*64*68*4 + 1.5KB = 53.8 KB -> 3 blocks/CU (was 2).
// ---------------------------------------------------------------------------
__global__ __launch_bounds__(256) void attn_kernel(
    const float* __restrict__ x_low,
    const float* __restrict__ gq, const float* __restrict__ bq,
    const float* __restrict__ gk, const float* __restrict__ bk,
    const float* __restrict__ qf, const float* __restrict__ kf,
    const float2* __restrict__ stats, float* __restrict__ out)
{
  // 2048 blocks, 8 XCDs: XCD x handles contiguous patches [x*256, (x+1)*256)
  const int n = ((blockIdx.x & 7) << 8) | (blockIdx.x >> 3);
  const int b = n >> 8;
  const int nl = n & 255;
  const int h0 = (nl >> 4) << 3, w0 = (nl & 15) << 3;
  const int t = threadIdx.x;
  const int tx = t & 15, ty = t >> 4;
  const int p = t & 63;     // pixel for softmax / store phases
  const int ci = t >> 6;    // 0..3

  __shared__ float q_ch[64][68];   // S: [c][pixel]; PV epilogue: s_out[pixel][c]
  __shared__ float k_ch[64][68];   // S: [c][pixel]; PV: kT[pixel(r)][c]
  __shared__ float s_mat[64][68];  // S^T then P^T: [r][p]
  __shared__ float red[4][64];
  __shared__ float rowstat[2][64]; // [0]=max [1]=sum over r, per p

  const int lc = t >> 2;           // 0..63 channel-local (staging)
  const int lp = (t & 3) << 4;     // pixel start (16 floats)

  const size_t kbase = (size_t)b * CS_N + ((size_t)nl << 6) + lp;  // + c*S_N
  const size_t pixoff =
      (size_t)b * CS_N + (size_t)(h0 + (p >> 3)) * W_N + (w0 + (p & 7));

  float accs[4][4];
#pragma unroll
  for (int i = 0; i < 4; ++i)
#pragma unroll
    for (int j = 0; j < 4; ++j) accs[i][j] = 0.0f;

  // ---- S accumulation over 4 channel chunks of 64 ----
  for (int chunk = 0; chunk < 4; ++chunk) {
    __syncthreads();
    {  // k: vector staging from patch-major kf, GN applied
      const int c = (chunk << 6) + lc;
      const float2 sk = stats[256 + (b << 5) + (c >> 3)];
      const float ksc = gk[c] * sk.y;
      const float ksh = bk[c] - sk.x * ksc;
      const float4* src = reinterpret_cast<const float4*>(kf + kbase + (size_t)c * S_N);
      const float4 v0 = src[0], v1 = src[1], v2 = src[2], v3 = src[3];
      float4* dst = reinterpret_cast<float4*>(&k_ch[lc][lp]);
      dst[0] = make_float4(fmaf(v0.x, ksc, ksh), fmaf(v0.y, ksc, ksh),
                           fmaf(v0.z, ksc, ksh), fmaf(v0.w, ksc, ksh));
      dst[1] = make_float4(fmaf(v1.x, ksc, ksh), fmaf(v1.y, ksc, ksh),
                           fmaf(v1.z, ksc, ksh), fmaf(v1.w, ksc, ksh));
      dst[2] = make_float4(fmaf(v2.x, ksc, ksh), fmaf(v2.y, ksc, ksh),
                           fmaf(v2.z, ksc, ksh), fmaf(v2.w, ksc, ksh));
      dst[3] = make_float4(fmaf(v3.x, ksc, ksh), fmaf(v3.y, ksc, ksh),
                           fmaf(v3.z, ksc, ksh), fmaf(v3.w, ksc, ksh));
    }
    // q: scalar transpose staging from standard-layout qf, GN applied.
    // The 1/sqrt(C)=1/16 attention scale is folded here (exact, power of 2).
    for (int cl = ci; cl < 64; cl += 4) {
      const int c = (chunk << 6) + cl;
      const float2 sq = stats[(b << 5) + (c >> 3)];
      const float qsc = gq[c] * sq.y * 0.0625f;
      const float qsh = (bq[c] - sq.x * gq[c] * sq.y) * 0.0625f;
      q_ch[cl][p] = fmaf(qf[pixoff + (size_t)c * S_N], qsc, qsh);
    }
    __syncthreads();
#pragma unroll 4
    for (int c = 0; c < 64; ++c) {
      const float4 qv = *reinterpret_cast<const float4*>(&q_ch[c][ty * 4]);
      const float4 kv = *reinterpret_cast<const float4*>(&k_ch[c][tx * 4]);
      const float qa[4] = {qv.x, qv.y, qv.z, qv.w};
      const float ka[4] = {kv.x, kv.y, kv.z, kv.w};
#pragma unroll
      for (int i = 0; i < 4; ++i)
#pragma unroll
        for (int j = 0; j < 4; ++j) accs[i][j] = fmaf(qa[i], ka[j], accs[i][j]);
    }
  }
  // store S transposed: s_mat[r][p] = S[p][r]
#pragma unroll
  for (int j = 0; j < 4; ++j)
    *reinterpret_cast<float4*>(&s_mat[tx * 4 + j][ty * 4]) =
        make_float4(accs[0][j], accs[1][j], accs[2][j], accs[3][j]);
  __syncthreads();

  // ---- softmax over r for each query pixel p (lane-contiguous reads) ----
  {
    float m = -3.0e38f;
#pragma unroll
    for (int rr = 0; rr < 16; ++rr) m = fmaxf(m, s_mat[ci * 16 + rr][p]);
    red[ci][p] = m;
    __syncthreads();
    if (t < 64)
      rowstat[0][t] = fmaxf(fmaxf(red[0][t], red[1][t]), fmaxf(red[2][t], red[3][t]));
    __syncthreads();
    const float rm = rowstat[0][p];
    float sum = 0.0f;
#pragma unroll
    for (int rr = 0; rr < 16; ++rr) {
      const float e = __expf(s_mat[ci * 16 + rr][p] - rm);
      s_mat[ci * 16 + rr][p] = e;
      sum += e;
    }
    red[ci][p] = sum;
    __syncthreads();
    if (t < 64) rowstat[1][t] = red[0][t] + red[1][t] + red[2][t] + red[3][t];
    __syncthreads();
  }
  const float rinv = 1.0f / rowstat[1][p];

  // ---- PV per channel chunk: out[p][c] = sum_r P[p][r] * k̂[c][r] ----
  for (int chunk = 0; chunk < 4; ++chunk) {
    __syncthreads();
    {  // restage k̂ transposed: k_ch[r][c]
      const int c = (chunk << 6) + lc;
      const float2 sk = stats[256 + (b << 5) + (c >> 3)];
      const float ksc = gk[c] * sk.y;
      const float ksh = bk[c] - sk.x * ksc;
      const float4* src = reinterpret_cast<const float4*>(kf + kbase + (size_t)c * S_N);
      const float4 v0 = src[0], v1 = src[1], v2 = src[2], v3 = src[3];
      const float vals[16] = {v0.x, v0.y, v0.z, v0.w, v1.x, v1.y, v1.z, v1.w,
                              v2.x, v2.y, v2.z, v2.w, v3.x, v3.y, v3.z, v3.w};
#pragma unroll
      for (int u = 0; u < 16; ++u) k_ch[lp + u][lc] = fmaf(vals[u], ksc, ksh);
    }
    __syncthreads();
    float accp[4][4];
#pragma unroll
    for (int i = 0; i < 4; ++i)
#pragma unroll
      for (int j = 0; j < 4; ++j) accp[i][j] = 0.0f;
#pragma unroll 4
    for (int r = 0; r < 64; ++r) {
      const float4 pv = *reinterpret_cast<const float4*>(&s_mat[r][ty * 4]);
      const float4 kv = *reinterpret_cast<const float4*>(&k_ch[r][tx * 4]);
      const float pa[4] = {pv.x, pv.y, pv.z, pv.w};
      const float ka[4] = {kv.x, kv.y, kv.z, kv.w};
#pragma unroll
      for (int i = 0; i < 4; ++i)
#pragma unroll
        for (int j = 0; j < 4; ++j) accp[i][j] = fmaf(pa[i], ka[j], accp[i][j]);
    }
    // stage to s_out (reuse q_ch; prior readers synced at loop top)
#pragma unroll
    for (int i = 0; i < 4; ++i)
      *reinterpret_cast<float4*>(&q_ch[ty * 4 + i][tx * 4]) =
          make_float4(accp[i][0], accp[i][1], accp[i][2], accp[i][3]);
    __syncthreads();
    for (int cl = ci; cl < 64; cl += 4) {
      const size_t a = pixoff + (size_t)((chunk << 6) + cl) * S_N;
      out[a] = fmaf(q_ch[p][cl], rinv, x_low[a]);
    }
  }
}

// ---------------------------------------------------------------------------
extern "C" void kernel_launch(void* const* d_in, const int* in_sizes, int n_in,
                              void* d_out, int out_size, void* d_ws, size_t ws_size,
                              hipStream_t stream)
{
  const float* x_low  = (const float*)d_in[0];
  const float* x_high = (const float*)d_in[1];
  const float* Wq     = (const float*)d_in[2];
  const float* gq     = (const float*)d_in[3];
  const float* bq     = (const float*)d_in[4];
  const float* bk_    = (const float*)d_in[7];
  const float* Wk     = (const float*)d_in[5];
  const float* gk     = (const float*)d_in[6];
  float* out = (float*)d_out;

  float* qf = out;                    // standard layout (same addresses attn later overwrites)
  float* kf = (float*)d_ws;           // patch-major layout, 128 MiB
  float2* stats = (float2*)((char*)d_ws + (size_t)NELEM * 4);  // 512 float2

  dim3 gconv(128, 2, 16);
  hipLaunchKernelGGL(conv_gemm, gconv, dim3(256), 0, stream,
                     x_low, x_high, Wq, Wk, qf, kf);
  hipLaunchKernelGGL(gn_stats, dim3(512), dim3(256), 0, stream, qf, kf, stats);
  hipLaunchKernelGGL(attn_kernel, dim3(2048), dim3(256), 0, stream,
                     x_low, gq, bq, gk, bk_, qf, kf, stats, out);
}

// Round 3
// 694.184 us; speedup vs baseline: 1.6136x; 1.2307x over previous
//
#include <hip/hip_runtime.h>
#include <cstdint>
#include <cstddef>

#define B_N   8
#define C_N   256
#define H_N   128
#define W_N   128
#define S_N   16384          // H*W
#define CS_N  4194304        // C*S
#define NELEM 33554432       // B*C*S
#define EPS_F 1e-5f

typedef __attribute__((ext_vector_type(8))) short short8;   // 8 bf16 = 4 VGPR
typedef __attribute__((ext_vector_type(4))) float f32x4;

union PackB { uint32_t w[4]; uint4 u4; short8 s8; };

// round-to-nearest-even fp32 -> bf16 (bits), finite inputs
__device__ __forceinline__ uint32_t bf16_rne(float x) {
  const uint32_t u = __float_as_uint(x);
  return (u + 0x7FFFu + ((u >> 16) & 1u)) >> 16;
}
// pack (hi|lo) split of x into one word: hi = bf16(x), lo = bf16(x - hi)
__device__ __forceinline__ uint32_t splitpack(float x) {
  const uint32_t hi = bf16_rne(x);
  const float r = x - __uint_as_float(hi << 16);
  const uint32_t lo = bf16_rne(r);
  return (hi << 16) | lo;
}
// LDS word-index swizzle: spreads 8 s-rows across 8 bank-quads
__device__ __forceinline__ int swz(int s, int c) {
  return (s * 64 + c) ^ (((s & 3) << 3) | (s & 4));
}

// ---------------------------------------------------------------------------
// Kernel 0: split W into bf16 hi/lo packed in per-lane MFMA fragment order.
// frag id f = ((tensor*8 + kf)*16 + mf)*2 + hl ; 1 KB per frag (64 lanes x 16B)
// lane's 8 bf16: o = mf*16 + (lane&15), c = kf*32 + (lane>>4)*8 + j
// ---------------------------------------------------------------------------
__global__ __launch_bounds__(256) void prep_w(
    const float* __restrict__ Wq, const float* __restrict__ Wk,
    uint4* __restrict__ wpk)
{
  const int gid = blockIdx.x * 256 + threadIdx.x;   // 32768 total
  const int lane = gid & 63;
  const int f = gid >> 6;                           // 0..511
  const int hl = f & 1;
  const int mf = (f >> 1) & 15;
  const int kf = (f >> 5) & 7;
  const int tensor = (f >> 8) & 1;
  const float* __restrict__ Wsrc = tensor ? Wk : Wq;

  const int o  = mf * 16 + (lane & 15);
  const int c0 = kf * 32 + ((lane >> 4) << 3);
  const float* src = Wsrc + (size_t)o * 256 + c0;
  const float4 x0 = *reinterpret_cast<const float4*>(src);
  const float4 x1 = *reinterpret_cast<const float4*>(src + 4);
  const float xs[8] = {x0.x, x0.y, x0.z, x0.w, x1.x, x1.y, x1.z, x1.w};

  uint32_t h[8];
#pragma unroll
  for (int e = 0; e < 8; ++e) {
    const uint32_t hi = bf16_rne(xs[e]);
    if (hl == 0) {
      h[e] = hi;
    } else {
      h[e] = bf16_rne(xs[e] - __uint_as_float(hi << 16));
    }
  }
  uint4 outw;
  outw.x = h[0] | (h[1] << 16);
  outw.y = h[2] | (h[3] << 16);
  outw.z = h[4] | (h[5] << 16);
  outw.w = h[6] | (h[7] << 16);
  wpk[(size_t)f * 64 + lane] = outw;
}

// ---------------------------------------------------------------------------
// Kernel 1: 1x1 conv as split-bf16 MFMA GEMM. Y[o][s] = sum_c W[o][c] X[c][s]
// block tile M=256 (all o) x N=64 (one patch), K-step 64, 4 waves (64x64 each).
// A (W) fragments loaded straight from pre-packed L2-resident wpk.
// B (X) split in-kernel -> LDS [s][c] packed (hi|lo) words, XOR swizzle,
// double-buffered; Y ~= Ahi*Bhi + Ahi*Blo + Alo*Bhi (fp32 accum in MFMA).
// Output layout: tensor 0 (qf=d_out) standard s ; tensor 1 (kf) patch-major.
// ---------------------------------------------------------------------------
__global__ __launch_bounds__(256) void conv_mfma(
    const float* __restrict__ x_low, const float* __restrict__ x_high,
    const uint4* __restrict__ wpk,
    float* __restrict__ qf, float* __restrict__ kf)
{
  const int t = threadIdx.x;
  const int lane = t & 63;
  const int w = t >> 6;                 // wave 0..3
  const int tile = blockIdx.x;          // s-tile 0..255 (= patch id for kf)
  const int bz = blockIdx.y;            // 0..15
  const int tensor = bz >> 3;
  const int b = bz & 7;

  const float* __restrict__ X = tensor ? x_high : x_low;
  float* __restrict__ Y = tensor ? kf : qf;
  const short8* __restrict__ wpkS = reinterpret_cast<const short8*>(wpk);

  const size_t xbase = (size_t)b * CS_N;
  const int s0 = tile * 64;

  __shared__ uint32_t xb[2][4096];      // [s(64)][c(64)] packed words, swizzled

  // ---- staging geometry: thread reads 16 consecutive output-s at one c ----
  const int cl = t >> 2;                // c_local 0..63
  const int sq = t & 3;                 // s-quarter
  int offA, offB;                       // element offsets of the two 8-f runs
  if (tensor) {
    const int rA = 2 * sq, rB = 2 * sq + 1;        // patch rows
    const int pb = ((tile >> 4) << 3) * W_N + ((tile & 15) << 3);
    offA = pb + rA * W_N;
    offB = pb + rB * W_N;
  } else {
    offA = s0 + sq * 16;
    offB = offA + 8;
  }
  const float* __restrict__ Xb = X + xbase;

  f32x4 acc[4][4] = {};

  // convert+write one staged register set into buffer nb
  auto stage_write = [&](const float4& A0, const float4& A1,
                         const float4& B0, const float4& B1, int nb) {
    const float v[16] = {A0.x, A0.y, A0.z, A0.w, A1.x, A1.y, A1.z, A1.w,
                         B0.x, B0.y, B0.z, B0.w, B1.x, B1.y, B1.z, B1.w};
#pragma unroll
    for (int jj = 0; jj < 16; ++jj) {
      const int sl = sq * 16 + jj;
      xb[nb][swz(sl, cl)] = splitpack(v[jj]);
    }
  };

  // prologue: stage kt=0 into buffer 0
  {
    const float* p = Xb + (size_t)cl * S_N;
    const float4 A0 = *reinterpret_cast<const float4*>(p + offA);
    const float4 A1 = *reinterpret_cast<const float4*>(p + offA + 4);
    const float4 B0 = *reinterpret_cast<const float4*>(p + offB);
    const float4 B1 = *reinterpret_cast<const float4*>(p + offB + 4);
    stage_write(A0, A1, B0, B1, 0);
  }

  for (int kt = 0; kt < 4; ++kt) {
    const int cur = kt & 1;
    __syncthreads();

    // issue next tile's global loads early (latency hides under MFMA)
    float4 nA0, nA1, nB0, nB1;
    if (kt < 3) {
      const float* p = Xb + (size_t)((kt + 1) * 64 + cl) * S_N;
      nA0 = *reinterpret_cast<const float4*>(p + offA);
      nA1 = *reinterpret_cast<const float4*>(p + offA + 4);
      nB0 = *reinterpret_cast<const float4*>(p + offB);
      nB1 = *reinterpret_cast<const float4*>(p + offB + 4);
    }

    // ---- compute 2 K32 steps from buf[cur] ----
#pragma unroll
    for (int ks = 0; ks < 2; ++ks) {
      const int kfrag = kt * 2 + ks;
      const int fbase = ((tensor * 8 + kfrag) * 16 + w * 4) * 2;
      short8 a_hi[4], a_lo[4];
#pragma unroll
      for (int mf = 0; mf < 4; ++mf) {
        a_hi[mf] = wpkS[(size_t)(fbase + mf * 2) * 64 + lane];
        a_lo[mf] = wpkS[(size_t)(fbase + mf * 2 + 1) * 64 + lane];
      }
      short8 b_hi[4], b_lo[4];
      const int c0 = ks * 32 + ((lane >> 4) << 3);
#pragma unroll
      for (int nf = 0; nf < 4; ++nf) {
        const int sl = nf * 16 + (lane & 15);
        const int wx = ((sl & 3) << 3) | (sl & 4);
        const int base1 = ((sl * 64 + c0) ^ wx);
        const int base2 = ((sl * 64 + c0 + 4) ^ wx);
        const uint4 u = *reinterpret_cast<const uint4*>(&xb[cur][base1]);
        const uint4 v = *reinterpret_cast<const uint4*>(&xb[cur][base2]);
        PackB ph, pl;
        ph.w[0] = __builtin_amdgcn_perm(u.y, u.x, 0x07060302u);
        ph.w[1] = __builtin_amdgcn_perm(u.w, u.z, 0x07060302u);
        ph.w[2] = __builtin_amdgcn_perm(v.y, v.x, 0x07060302u);
        ph.w[3] = __builtin_amdgcn_perm(v.w, v.z, 0x07060302u);
        pl.w[0] = __builtin_amdgcn_perm(u.y, u.x, 0x05040100u);
        pl.w[1] = __builtin_amdgcn_perm(u.w, u.z, 0x05040100u);
        pl.w[2] = __builtin_amdgcn_perm(v.y, v.x, 0x05040100u);
        pl.w[3] = __builtin_amdgcn_perm(v.w, v.z, 0x05040100u);
        b_hi[nf] = ph.s8;
        b_lo[nf] = pl.s8;
      }
#pragma unroll
      for (int mf = 0; mf < 4; ++mf)
#pragma unroll
        for (int nf = 0; nf < 4; ++nf) {
          acc[mf][nf] = __builtin_amdgcn_mfma_f32_16x16x32_bf16(
              a_hi[mf], b_hi[nf], acc[mf][nf], 0, 0, 0);
          acc[mf][nf] = __builtin_amdgcn_mfma_f32_16x16x32_bf16(
              a_hi[mf], b_lo[nf], acc[mf][nf], 0, 0, 0);
          acc[mf][nf] = __builtin_amdgcn_mfma_f32_16x16x32_bf16(
              a_lo[mf], b_hi[nf], acc[mf][nf], 0, 0, 0);
        }
    }

    if (kt < 3) stage_write(nA0, nA1, nB0, nB1, cur ^ 1);
  }

  // ---- epilogue: D col = lane&15 (s), row = (lane>>4)*4 + reg (o) ----
  const int orow = w * 64 + ((lane >> 4) << 2);
  const int scol = s0 + (lane & 15);
#pragma unroll
  for (int mf = 0; mf < 4; ++mf)
#pragma unroll
    for (int nf = 0; nf < 4; ++nf) {
      const int o = orow + mf * 16;
      const int s = scol + nf * 16;
#pragma unroll
      for (int r = 0; r < 4; ++r)
        Y[xbase + (size_t)(o + r) * S_N + s] = acc[mf][nf][r];
    }
}

// ---------------------------------------------------------------------------
// Kernel 2: GroupNorm stats. One block per (tensor, b, g).
// Sums are invariant to the spatial permutation of kf, so unchanged.
// ---------------------------------------------------------------------------
__global__ __launch_bounds__(256) void gn_stats(
    const float* __restrict__ qf, const float* __restrict__ kf,
    float2* __restrict__ stats)
{
  const int bid = blockIdx.x;            // 0..511
  const int tensor = bid >> 8;
  const int rem = bid & 255;
  const int b = rem >> 5;
  const int g = rem & 31;
  const float* __restrict__ base =
      (tensor ? kf : qf) + (size_t)b * CS_N + (size_t)g * 8 * S_N;
  const float4* __restrict__ base4 = reinterpret_cast<const float4*>(base);

  const int tid = threadIdx.x;
  float s1 = 0.0f, s2 = 0.0f;
  for (int i = tid; i < 32768; i += 256) {
    const float4 u = base4[i];
    s1 += u.x + u.y + u.z + u.w;
    s2 += u.x * u.x + u.y * u.y + u.z * u.z + u.w * u.w;
  }
#pragma unroll
  for (int off = 32; off > 0; off >>= 1) {
    s1 += __shfl_down(s1, off);
    s2 += __shfl_down(s2, off);
  }
  __shared__ float r1[4], r2[4];
  const int wave = tid >> 6;
  if ((tid & 63) == 0) { r1[wave] = s1; r2[wave] = s2; }
  __syncthreads();
  if (tid == 0) {
    const float S1 = r1[0] + r1[1] + r1[2] + r1[3];
    const float S2 = r2[0] + r2[1] + r2[2] + r2[3];
    const float mean = S1 * (1.0f / 131072.0f);
    const float var = S2 * (1.0f / 131072.0f) - mean * mean;
    stats[bid] = make_float2(mean, rsqrtf(var + EPS_F));
  }
}

// ---------------------------------------------------------------------------
// Kernel 3: per-patch attention (unchanged from verified round-2 kernel).
// ---------------------------------------------------------------------------
__global__ __launch_bounds__(256) void attn_kernel(
    const float* __restrict__ x_low,
    const float* __restrict__ gq, const float* __restrict__ bq,
    const float* __restrict__ gk, const float* __restrict__ bk,
    const float* __restrict__ qf, const float* __restrict__ kf,
    const float2* __restrict__ stats, float* __restrict__ out)
{
  const int n = ((blockIdx.x & 7) << 8) | (blockIdx.x >> 3);
  const int b = n >> 8;
  const int nl = n & 255;
  const int h0 = (nl >> 4) << 3, w0 = (nl & 15) << 3;
  const int t = threadIdx.x;
  const int tx = t & 15, ty = t >> 4;
  const int p = t & 63;
  const int ci = t >> 6;

  __shared__ float q_ch[64][68];
  __shared__ float k_ch[64][68];
  __shared__ float s_mat[64][68];
  __shared__ float red[4][64];
  __shared__ float rowstat[2][64];

  const int lc = t >> 2;
  const int lp = (t & 3) << 4;

  const size_t kbase = (size_t)b * CS_N + ((size_t)nl << 6) + lp;
  const size_t pixoff =
      (size_t)b * CS_N + (size_t)(h0 + (p >> 3)) * W_N + (w0 + (p & 7));

  float accs[4][4];
#pragma unroll
  for (int i = 0; i < 4; ++i)
#pragma unroll
    for (int j = 0; j < 4; ++j) accs[i][j] = 0.0f;

  for (int chunk = 0; chunk < 4; ++chunk) {
    __syncthreads();
    {
      const int c = (chunk << 6) + lc;
      const float2 sk = stats[256 + (b << 5) + (c >> 3)];
      const float ksc = gk[c] * sk.y;
      const float ksh = bk[c] - sk.x * ksc;
      const float4* src = reinterpret_cast<const float4*>(kf + kbase + (size_t)c * S_N);
      const float4 v0 = src[0], v1 = src[1], v2 = src[2], v3 = src[3];
      float4* dst = reinterpret_cast<float4*>(&k_ch[lc][lp]);
      dst[0] = make_float4(fmaf(v0.x, ksc, ksh), fmaf(v0.y, ksc, ksh),
                           fmaf(v0.z, ksc, ksh), fmaf(v0.w, ksc, ksh));
      dst[1] = make_float4(fmaf(v1.x, ksc, ksh), fmaf(v1.y, ksc, ksh),
                           fmaf(v1.z, ksc, ksh), fmaf(v1.w, ksc, ksh));
      dst[2] = make_float4(fmaf(v2.x, ksc, ksh), fmaf(v2.y, ksc, ksh),
                           fmaf(v2.z, ksc, ksh), fmaf(v2.w, ksc, ksh));
      dst[3] = make_float4(fmaf(v3.x, ksc, ksh), fmaf(v3.y, ksc, ksh),
                           fmaf(v3.z, ksc, ksh), fmaf(v3.w, ksc, ksh));
    }
    for (int cl = ci; cl < 64; cl += 4) {
      const int c = (chunk << 6) + cl;
      const float2 sq = stats[(b << 5) + (c >> 3)];
      const float qsc = gq[c] * sq.y * 0.0625f;
      const float qsh = (bq[c] - sq.x * gq[c] * sq.y) * 0.0625f;
      q_ch[cl][p] = fmaf(qf[pixoff + (size_t)c * S_N], qsc, qsh);
    }
    __syncthreads();
#pragma unroll 4
    for (int c = 0; c < 64; ++c) {
      const float4 qv = *reinterpret_cast<const float4*>(&q_ch[c][ty * 4]);
      const float4 kv = *reinterpret_cast<const float4*>(&k_ch[c][tx * 4]);
      const float qa[4] = {qv.x, qv.y, qv.z, qv.w};
      const float ka[4] = {kv.x, kv.y, kv.z, kv.w};
#pragma unroll
      for (int i = 0; i < 4; ++i)
#pragma unroll
        for (int j = 0; j < 4; ++j) accs[i][j] = fmaf(qa[i], ka[j], accs[i][j]);
    }
  }
#pragma unroll
  for (int j = 0; j < 4; ++j)
    *reinterpret_cast<float4*>(&s_mat[tx * 4 + j][ty * 4]) =
        make_float4(accs[0][j], accs[1][j], accs[2][j], accs[3][j]);
  __syncthreads();

  {
    float m = -3.0e38f;
#pragma unroll
    for (int rr = 0; rr < 16; ++rr) m = fmaxf(m, s_mat[ci * 16 + rr][p]);
    red[ci][p] = m;
    __syncthreads();
    if (t < 64)
      rowstat[0][t] = fmaxf(fmaxf(red[0][t], red[1][t]), fmaxf(red[2][t], red[3][t]));
    __syncthreads();
    const float rm = rowstat[0][p];
    float sum = 0.0f;
#pragma unroll
    for (int rr = 0; rr < 16; ++rr) {
      const float e = __expf(s_mat[ci * 16 + rr][p] - rm);
      s_mat[ci * 16 + rr][p] = e;
      sum += e;
    }
    red[ci][p] = sum;
    __syncthreads();
    if (t < 64) rowstat[1][t] = red[0][t] + red[1][t] + red[2][t] + red[3][t];
    __syncthreads();
  }
  const float rinv = 1.0f / rowstat[1][p];

  for (int chunk = 0; chunk < 4; ++chunk) {
    __syncthreads();
    {
      const int c = (chunk << 6) + lc;
      const float2 sk = stats[256 + (b << 5) + (c >> 3)];
      const float ksc = gk[c] * sk.y;
      const float ksh = bk[c] - sk.x * ksc;
      const float4* src = reinterpret_cast<const float4*>(kf + kbase + (size_t)c * S_N);
      const float4 v0 = src[0], v1 = src[1], v2 = src[2], v3 = src[3];
      const float vals[16] = {v0.x, v0.y, v0.z, v0.w, v1.x, v1.y, v1.z, v1.w,
                              v2.x, v2.y, v2.z, v2.w, v3.x, v3.y, v3.z, v3.w};
#pragma unroll
      for (int u = 0; u < 16; ++u) k_ch[lp + u][lc] = fmaf(vals[u], ksc, ksh);
    }
    __syncthreads();
    float accp[4][4];
#pragma unroll
    for (int i = 0; i < 4; ++i)
#pragma unroll
      for (int j = 0; j < 4; ++j) accp[i][j] = 0.0f;
#pragma unroll 4
    for (int r = 0; r < 64; ++r) {
      const float4 pv = *reinterpret_cast<const float4*>(&s_mat[r][ty * 4]);
      const float4 kv = *reinterpret_cast<const float4*>(&k_ch[r][tx * 4]);
      const float pa[4] = {pv.x, pv.y, pv.z, pv.w};
      const float ka[4] = {kv.x, kv.y, kv.z, kv.w};
#pragma unroll
      for (int i = 0; i < 4; ++i)
#pragma unroll
        for (int j = 0; j < 4; ++j) accp[i][j] = fmaf(pa[i], ka[j], accp[i][j]);
    }
#pragma unroll
    for (int i = 0; i < 4; ++i)
      *reinterpret_cast<float4*>(&q_ch[ty * 4 + i][tx * 4]) =
          make_float4(accp[i][0], accp[i][1], accp[i][2], accp[i][3]);
    __syncthreads();
    for (int cl = ci; cl < 64; cl += 4) {
      const size_t a = pixoff + (size_t)((chunk << 6) + cl) * S_N;
      out[a] = fmaf(q_ch[p][cl], rinv, x_low[a]);
    }
  }
}

// ---------------------------------------------------------------------------
extern "C" void kernel_launch(void* const* d_in, const int* in_sizes, int n_in,
                              void* d_out, int out_size, void* d_ws, size_t ws_size,
                              hipStream_t stream)
{
  const float* x_low  = (const float*)d_in[0];
  const float* x_high = (const float*)d_in[1];
  const float* Wq     = (const float*)d_in[2];
  const float* gq     = (const float*)d_in[3];
  const float* bq     = (const float*)d_in[4];
  const float* Wk     = (const float*)d_in[5];
  const float* gk     = (const float*)d_in[6];
  const float* bk     = (const float*)d_in[7];
  float* out = (float*)d_out;

  float* qf = out;                    // standard layout (attn overwrites same addrs)
  float* kf = (float*)d_ws;           // patch-major layout, 128 MiB
  float2* stats = (float2*)((char*)d_ws + (size_t)NELEM * 4);      // 4 KB
  uint4* wpk = (uint4*)((char*)d_ws + (size_t)NELEM * 4 + 4096);   // 512 KB

  hipLaunchKernelGGL(prep_w, dim3(128), dim3(256), 0, stream, Wq, Wk, wpk);
  hipLaunchKernelGGL(conv_mfma, dim3(256, 16), dim3(256), 0, stream,
                     x_low, x_high, wpk, qf, kf);
  hipLaunchKernelGGL(gn_stats, dim3(512), dim3(256), 0, stream, qf, kf, stats);
  hipLaunchKernelGGL(attn_kernel, dim3(2048), dim3(256), 0, stream,
                     x_low, gq, bq, gk, bk, qf, kf, stats, out);
}